// Round 4
// baseline (237.570 us; speedup 1.0000x reference)
//
#include <hip/hip_runtime.h>
#include <hip/hip_fp16.h>

// TwoDimensionalSSM via direct 2D recurrence. Round 10: occupancy granularity.
// R9 post-mortem: fused fmac-dpp scans + fp16 u_lds -> 176->143us, VGPR 60,
// LDS 32KB. Cross-round evidence says LATENCY-bound, not issue-bound:
//  - R8 cut static VALU 35% -> dur UP; R9's win tracked the LDS cut.
//  - VALUBusy is a gfx94x-formula fallback (no gfx950 section in ROCm 7.2
//    derived_counters.xml); if it assumes SIMD-16 (4cyc/inst) on a SIMD-32
//    chip it overstates ~2x: true busy ~40-50%, matching static count.
// Fix this round (single variable): NPB 8->4, THREADS 256->128.
// Block LDS 32->16KB -> 10 blocks/CU = 20 waves/CU = 5 waves/SIMD (was ~3),
// 4096 blocks halve tail quantization. All math/scan/swizzle logic identical.

#define NPB 4            // images per block (one per 32-lane half, 2/wave)
#define THREADS 128
#define M_TOT 16384      // B*E
#define SCALE 0.70710678118654752f  // sqrt(1/N), N=2

typedef __attribute__((ext_vector_type(2))) float v2f;

__device__ __forceinline__ v2f v2s(float s) { return (v2f){s, s}; }
__device__ __forceinline__ v2f pfma(v2f a, v2f b, v2f c) {
    return __builtin_elementwise_fma(a, b, c);   // -> v_pk_fma_f32
}

template<int CTRL, int ROW_MASK, bool BC>
__device__ __forceinline__ float dppf(float v) {
    return __int_as_float(__builtin_amdgcn_update_dpp(
        0, __float_as_int(v), CTRL, ROW_MASK, 0xF, BC));
}
template<int CTRL, int ROW_MASK, bool BC>
__device__ __forceinline__ v2f dpp2(v2f v) {
    v2f r;
    r.x = dppf<CTRL, ROW_MASK, BC>(v.x);
    r.y = dppf<CTRL, ROW_MASK, BC>(v.y);
    return r;
}
__device__ __forceinline__ v2f swz2(v2f v) {   // lane16 of each 32-half
    v2f r;
    r.x = __int_as_float(__builtin_amdgcn_ds_swizzle(__float_as_int(v.x), 0x0200));
    r.y = __int_as_float(__builtin_amdgcn_ds_swizzle(__float_as_int(v.y), 0x0200));
    return r;
}

__device__ __forceinline__ float sigm(float v) { return 1.0f / (1.0f + __expf(-v)); }

struct DirP2 {
    v2f a1, p2, p4, p8, w;        // scan coefficients
    v2f a2z, ab, a3, a4, b1, b2, a3b1, c1s, c2s;
    float k00;
};

template<bool REV>
__device__ __forceinline__ void dir_init2(DirP2& P, int h, int j,
    const float* __restrict__ A1p, const float* __restrict__ A2p,
    const float* __restrict__ A3p, const float* __restrict__ A4p,
    const float* __restrict__ B1p, const float* __restrict__ B2p,
    const float* __restrict__ C1p, const float* __restrict__ C2p)
{
    float2 a1r = *(const float2*)(A1p + 2 * h);
    float2 a2r = *(const float2*)(A2p + 2 * h);
    float2 a3r = *(const float2*)(A3p + 2 * h);
    float2 a4r = *(const float2*)(A4p + 2 * h);
    float2 b1r = *(const float2*)(B1p + 2 * h);
    float2 b2r = *(const float2*)(B2p + 2 * h);
    float2 c1r = *(const float2*)(C1p + 2 * h);
    float2 c2r = *(const float2*)(C2p + 2 * h);
    float a1v0 = sigm(a1r.x), a1v1 = sigm(a1r.y);
    P.a1 = (v2f){a1v0, a1v1};
    P.p2 = P.a1 * P.a1; P.p4 = P.p2 * P.p2; P.p8 = P.p4 * P.p4;
    P.a3 = (v2f){sigm(a3r.x), sigm(a3r.y)};
    P.a4 = (v2f){sigm(a4r.x), sigm(a4r.y)};
    P.b1 = (v2f){sigm(b1r.x), sigm(b1r.y)};
    P.b2 = (v2f){sigm(b2r.x), sigm(b2r.y)};
    P.a3b1 = P.a3 * P.b1;
    P.c1s = (v2f){SCALE * c1r.x, SCALE * c1r.y};
    P.c2s = (v2f){SCALE * c2r.x, SCALE * c2r.y};
    v2f kk = P.c1s * P.b1 + P.c2s * P.b2;
    P.k00 = kk.x + kk.y;
    // boundary kill: fwd at j==0 (also kills wave_shr cross-half leak),
    // rev at j==31 (kills wave_shl cross-half leak). Per-lane.
    const bool edge = REV ? (j == 31) : (j == 0);
    v2f a2n = (v2f){sigm(a2r.x), sigm(a2r.y)};
    P.a2z = edge ? (v2f){0.f, 0.f} : a2n;
    P.ab  = P.a2z * P.b2;
    if (REV) {
        if ((j & 16) == 0) {
            float e = (float)(16 - (j & 15));
            P.w = (v2f){__powf(a1v0, e), __powf(a1v1, e)};
        } else {
            P.w = (v2f){0.f, 0.f};
        }
    } else {
        float e = (float)((j & 15) + 1);
        P.w = (v2f){__powf(a1v0, e), __powf(a1v1, e)};
    }
}

// recurrence front-end: produce nxv, ncx and the two scan inputs d, e
template<bool REV>
__device__ __forceinline__ void dir_pre(const DirP2& P, v2f u2, v2f up2,
    v2f xh, v2f xv, v2f cx, v2f& nxv, v2f& ncx, v2f& d, v2f& e)
{
    v2f b2u = P.b2 * u2;
    nxv = pfma(P.a3, xh, pfma(P.a4, xv, b2u));
    ncx = pfma(P.a3b1, up2, pfma(P.a4, cx, b2u));
    v2f xl, ul2;
    if constexpr (REV) {   // neighbor = column j+1 -> wave_shl:1
        xl  = dpp2<0x130, 0xF, true>(nxv);
        ul2 = dpp2<0x130, 0xF, true>(u2);
    } else {               // neighbor = column j-1 -> wave_shr:1
        xl  = dpp2<0x138, 0xF, true>(nxv);
        ul2 = dpp2<0x138, 0xF, true>(u2);
    }
    v2f b1u = P.b1 * u2;
    d = pfma(P.a2z, xl, b1u);
    e = pfma(P.ab, ul2, b1u);
}

// dot + state update
__device__ __forceinline__ float dir_post(const DirP2& P, v2f nh, v2f rh,
    v2f nxv, v2f ncx, v2f& xh, v2f& xv, v2f& cx)
{
    v2f acc = pfma(P.c1s, nh + rh, P.c2s * (nxv + ncx));
    xh = nh; xv = nxv; cx = ncx;
    return acc.x + acc.y;
}

// 8 interleaved scan chains: f* = fwd (row_shr + bcast15), r* = rev
// (row_shl; lane16-broadcast tail done by caller via ds_swizzle).
// One v_fmac_f32_dpp per stage per chain; 8-wide interleave covers the
// DPP read-after-VALU-write hazard; s_nop 1 covers the asm entry edge.
__device__ __forceinline__ void scan8(
    float& f0, float& f1, float& f2, float& f3,
    float& r0, float& r1, float& r2, float& r3,
    const DirP2& PF, const DirP2& PR)
{
    asm("s_nop 1\n\t"
        // ---- stage 1 ----
        "v_fmac_f32_dpp %0, %0, %8  row_shr:1 row_mask:0xf bank_mask:0xf bound_ctrl:0\n\t"
        "v_fmac_f32_dpp %1, %1, %9  row_shr:1 row_mask:0xf bank_mask:0xf bound_ctrl:0\n\t"
        "v_fmac_f32_dpp %2, %2, %8  row_shr:1 row_mask:0xf bank_mask:0xf bound_ctrl:0\n\t"
        "v_fmac_f32_dpp %3, %3, %9  row_shr:1 row_mask:0xf bank_mask:0xf bound_ctrl:0\n\t"
        "v_fmac_f32_dpp %4, %4, %18 row_shl:1 row_mask:0xf bank_mask:0xf bound_ctrl:0\n\t"
        "v_fmac_f32_dpp %5, %5, %19 row_shl:1 row_mask:0xf bank_mask:0xf bound_ctrl:0\n\t"
        "v_fmac_f32_dpp %6, %6, %18 row_shl:1 row_mask:0xf bank_mask:0xf bound_ctrl:0\n\t"
        "v_fmac_f32_dpp %7, %7, %19 row_shl:1 row_mask:0xf bank_mask:0xf bound_ctrl:0\n\t"
        // ---- stage 2 ----
        "v_fmac_f32_dpp %0, %0, %10 row_shr:2 row_mask:0xf bank_mask:0xf bound_ctrl:0\n\t"
        "v_fmac_f32_dpp %1, %1, %11 row_shr:2 row_mask:0xf bank_mask:0xf bound_ctrl:0\n\t"
        "v_fmac_f32_dpp %2, %2, %10 row_shr:2 row_mask:0xf bank_mask:0xf bound_ctrl:0\n\t"
        "v_fmac_f32_dpp %3, %3, %11 row_shr:2 row_mask:0xf bank_mask:0xf bound_ctrl:0\n\t"
        "v_fmac_f32_dpp %4, %4, %20 row_shl:2 row_mask:0xf bank_mask:0xf bound_ctrl:0\n\t"
        "v_fmac_f32_dpp %5, %5, %21 row_shl:2 row_mask:0xf bank_mask:0xf bound_ctrl:0\n\t"
        "v_fmac_f32_dpp %6, %6, %20 row_shl:2 row_mask:0xf bank_mask:0xf bound_ctrl:0\n\t"
        "v_fmac_f32_dpp %7, %7, %21 row_shl:2 row_mask:0xf bank_mask:0xf bound_ctrl:0\n\t"
        // ---- stage 3 ----
        "v_fmac_f32_dpp %0, %0, %12 row_shr:4 row_mask:0xf bank_mask:0xf bound_ctrl:0\n\t"
        "v_fmac_f32_dpp %1, %1, %13 row_shr:4 row_mask:0xf bank_mask:0xf bound_ctrl:0\n\t"
        "v_fmac_f32_dpp %2, %2, %12 row_shr:4 row_mask:0xf bank_mask:0xf bound_ctrl:0\n\t"
        "v_fmac_f32_dpp %3, %3, %13 row_shr:4 row_mask:0xf bank_mask:0xf bound_ctrl:0\n\t"
        "v_fmac_f32_dpp %4, %4, %22 row_shl:4 row_mask:0xf bank_mask:0xf bound_ctrl:0\n\t"
        "v_fmac_f32_dpp %5, %5, %23 row_shl:4 row_mask:0xf bank_mask:0xf bound_ctrl:0\n\t"
        "v_fmac_f32_dpp %6, %6, %22 row_shl:4 row_mask:0xf bank_mask:0xf bound_ctrl:0\n\t"
        "v_fmac_f32_dpp %7, %7, %23 row_shl:4 row_mask:0xf bank_mask:0xf bound_ctrl:0\n\t"
        // ---- stage 4 ----
        "v_fmac_f32_dpp %0, %0, %14 row_shr:8 row_mask:0xf bank_mask:0xf bound_ctrl:0\n\t"
        "v_fmac_f32_dpp %1, %1, %15 row_shr:8 row_mask:0xf bank_mask:0xf bound_ctrl:0\n\t"
        "v_fmac_f32_dpp %2, %2, %14 row_shr:8 row_mask:0xf bank_mask:0xf bound_ctrl:0\n\t"
        "v_fmac_f32_dpp %3, %3, %15 row_shr:8 row_mask:0xf bank_mask:0xf bound_ctrl:0\n\t"
        "v_fmac_f32_dpp %4, %4, %24 row_shl:8 row_mask:0xf bank_mask:0xf bound_ctrl:0\n\t"
        "v_fmac_f32_dpp %5, %5, %25 row_shl:8 row_mask:0xf bank_mask:0xf bound_ctrl:0\n\t"
        "v_fmac_f32_dpp %6, %6, %24 row_shl:8 row_mask:0xf bank_mask:0xf bound_ctrl:0\n\t"
        "v_fmac_f32_dpp %7, %7, %25 row_shl:8 row_mask:0xf bank_mask:0xf bound_ctrl:0\n\t"
        // ---- stage 5, fwd only: rows 1,3 += w * lane15-of-prev-row ----
        "v_fmac_f32_dpp %0, %0, %16 row_bcast:15 row_mask:0xa bank_mask:0xf bound_ctrl:0\n\t"
        "v_fmac_f32_dpp %1, %1, %17 row_bcast:15 row_mask:0xa bank_mask:0xf bound_ctrl:0\n\t"
        "v_fmac_f32_dpp %2, %2, %16 row_bcast:15 row_mask:0xa bank_mask:0xf bound_ctrl:0\n\t"
        "v_fmac_f32_dpp %3, %3, %17 row_bcast:15 row_mask:0xa bank_mask:0xf bound_ctrl:0"
        : "+v"(f0), "+v"(f1), "+v"(f2), "+v"(f3),
          "+v"(r0), "+v"(r1), "+v"(r2), "+v"(r3)
        : "v"(PF.a1.x), "v"(PF.a1.y), "v"(PF.p2.x), "v"(PF.p2.y),
          "v"(PF.p4.x), "v"(PF.p4.y), "v"(PF.p8.x), "v"(PF.p8.y),
          "v"(PF.w.x),  "v"(PF.w.y),
          "v"(PR.a1.x), "v"(PR.a1.y), "v"(PR.p2.x), "v"(PR.p2.y),
          "v"(PR.p4.x), "v"(PR.p4.y), "v"(PR.p8.x), "v"(PR.p8.y));
}

__global__ __launch_bounds__(THREADS) void ssm2d_kernel(
    const float* __restrict__ x,
    const float* __restrict__ A1p, const float* __restrict__ A2p,
    const float* __restrict__ A3p, const float* __restrict__ A4p,
    const float* __restrict__ B1p, const float* __restrict__ B2p,
    const float* __restrict__ C1p, const float* __restrict__ C2p,
    const float* __restrict__ omega,
    float* __restrict__ out)
{
    __shared__ __half u_lds[NPB * 1024];   // 8 KB fp16 input, XOR-swizzled
    __shared__ __half a_lds[NPB * 1024];   // 8 KB fp16 accumulator
    const int t = threadIdx.x;
    // XCD-aware remap: same-XCD blocks (bid&7 fixed) cover contiguous m-ranges
    const int bid = blockIdx.x;
    const int m0  = ((bid & 7) * 512 + (bid >> 3)) * NPB;

    // ---- stage x into LDS (f32 -> fp16); XOR swizzle kills conflicts ----
    const int simg = t & 3;
    #pragma unroll 4
    for (int it = 0; it < 32; ++it) {
        int pix = it * 32 + (t >> 2);
        u_lds[simg * 1024 + (pix ^ (simg << 2))] =
            __float2half(x[(size_t)pix * M_TOT + (m0 + simg)]);
    }
    __syncthreads();

    const int j    = t & 31;
    const int img  = t >> 5;              // 0..3
    const int m    = m0 + img;
    const int hb   = m & 63;
    const int colx = j ^ (img << 2);      // per-lane swizzled column
    const __half* uim = u_lds + img * 1024;
    __half*       aim = a_lds + img * 1024;
    const float om = omega[m & 1023];

    // ============ pass A: rows ascending, d0 (fwd) + d2 (rev) ============
    {
        DirP2 P0, P2;
        dir_init2<false>(P0, hb,       j, A1p, A2p, A3p, A4p, B1p, B2p, C1p, C2p);
        dir_init2<true >(P2, 128 + hb, j, A1p, A2p, A3p, A4p, B1p, B2p, C1p, C2p);
        const float omA = om - P0.k00 - P2.k00;   // fold both -k00*u terms
        v2f xhF = {0,0}, xvF = {0,0}, cxF = {0,0};
        v2f xhR = {0,0}, xvR = {0,0}, cxR = {0,0};
        float up = 0.f;
        #pragma unroll 4
        for (int s = 0; s < 32; ++s) {
            float u  = __half2float(uim[s * 32 + colx]);
            v2f u2 = v2s(u), up2 = v2s(up);
            v2f nxvF, ncxF, dF, eF, nxvR, ncxR, dR, eR;
            dir_pre<false>(P0, u2, up2, xhF, xvF, cxF, nxvF, ncxF, dF, eF);
            dir_pre<true >(P2, u2, up2, xhR, xvR, cxR, nxvR, ncxR, dR, eR);
            float f0 = dF.x, f1 = dF.y, f2 = eF.x, f3 = eF.y;
            float r0 = dR.x, r1 = dR.y, r2 = eR.x, r3 = eR.y;
            scan8(f0, f1, f2, f3, r0, r1, r2, r3, P0, P2);
            v2f nhF = {f0, f1}, rhF = {f2, f3};
            v2f dRv = {r0, r1}, eRv = {r2, r3};
            dRv = pfma(P2.w, swz2(dRv), dRv);   // rev tail: lane16 broadcast
            eRv = pfma(P2.w, swz2(eRv), eRv);
            float y0 = dir_post(P0, nhF, rhF, nxvF, ncxF, xhF, xvF, cxF);
            float y2 = dir_post(P2, dRv, eRv, nxvR, ncxR, xhR, xvR, cxR);
            aim[s * 32 + colx] = __float2half(fmaf(u, omA, y0 + y2));
            up = u;
        }
    }
    // ==== pass B: rows descending, d1 (fwd) + d3 (rev) + SiLU finalize ====
    {
        DirP2 P1, P3;
        dir_init2<false>(P1, 64 + hb,  j, A1p, A2p, A3p, A4p, B1p, B2p, C1p, C2p);
        dir_init2<true >(P3, 192 + hb, j, A1p, A2p, A3p, A4p, B1p, B2p, C1p, C2p);
        const float kB = P1.k00 + P3.k00;
        v2f xhF = {0,0}, xvF = {0,0}, cxF = {0,0};
        v2f xhR = {0,0}, xvR = {0,0}, cxR = {0,0};
        float up = 0.f;
        #pragma unroll 4
        for (int s = 0; s < 32; ++s) {
            int   r  = 31 - s;
            float u  = __half2float(uim[r * 32 + colx]);
            v2f u2 = v2s(u), up2 = v2s(up);
            v2f nxvF, ncxF, dF, eF, nxvR, ncxR, dR, eR;
            dir_pre<false>(P1, u2, up2, xhF, xvF, cxF, nxvF, ncxF, dF, eF);
            dir_pre<true >(P3, u2, up2, xhR, xvR, cxR, nxvR, ncxR, dR, eR);
            float f0 = dF.x, f1 = dF.y, f2 = eF.x, f3 = eF.y;
            float r0 = dR.x, r1 = dR.y, r2 = eR.x, r3 = eR.y;
            scan8(f0, f1, f2, f3, r0, r1, r2, r3, P1, P3);
            v2f nhF = {f0, f1}, rhF = {f2, f3};
            v2f dRv = {r0, r1}, eRv = {r2, r3};
            dRv = pfma(P3.w, swz2(dRv), dRv);
            eRv = pfma(P3.w, swz2(eRv), eRv);
            float y1 = dir_post(P1, nhF, rhF, nxvF, ncxF, xhF, xvF, cxF);
            float y3 = dir_post(P3, dRv, eRv, nxvR, ncxR, xhR, xvR, cxR);
            float z  = __half2float(aim[r * 32 + colx]) + y1 + y3;
            z = fmaf(u, -kB, z);
            float sg = 1.0f / (1.0f + __expf(-z));
            aim[r * 32 + colx] = __float2half(z * sg);   // in-place finalize
            up = u;
        }
    }
    __syncthreads();

    // ---- coalesced store-out (fp16 -> f32) ----
    #pragma unroll 4
    for (int it = 0; it < 32; ++it) {
        int pix = it * 32 + (t >> 2);
        out[(size_t)pix * M_TOT + (m0 + simg)] =
            __half2float(a_lds[simg * 1024 + (pix ^ (simg << 2))]);
    }
}

extern "C" void kernel_launch(void* const* d_in, const int* in_sizes, int n_in,
                              void* d_out, int out_size, void* d_ws, size_t ws_size,
                              hipStream_t stream) {
    const float* x  = (const float*)d_in[0];
    const float* A1 = (const float*)d_in[1];
    const float* A2 = (const float*)d_in[2];
    const float* A3 = (const float*)d_in[3];
    const float* A4 = (const float*)d_in[4];
    const float* B1 = (const float*)d_in[5];
    const float* B2 = (const float*)d_in[6];
    const float* C1 = (const float*)d_in[7];
    const float* C2 = (const float*)d_in[8];
    const float* om = (const float*)d_in[9];
    float* out = (float*)d_out;
    hipLaunchKernelGGL(ssm2d_kernel, dim3(M_TOT / NPB), dim3(THREADS), 0, stream,
                       x, A1, A2, A3, A4, B1, B2, C1, C2, om, out);
}

// Round 5
// 227.105 us; speedup vs baseline: 1.0461x; 1.0461x over previous
//
#include <hip/hip_runtime.h>
#include <hip/hip_fp16.h>

// TwoDimensionalSSM via direct 2D recurrence. Round 11: reversed-lane rev
// directions -> ds_swizzle off the critical chain.
// R10 post-mortem: NPB=4 regressed (1M bank conflicts from broken staging
// swizzle; occupancy did NOT rise despite 16KB LDS -> occupancy-granularity
// theory dead). Reverted to R9 config (NPB=8, 256 thr, 32KB LDS).
// R11 theory: loop is bound by the REV dirs' cross-row chain, whose scan tail
// (lane16 broadcast) was a ds_swizzle = ~60-120cyc lgkm wait INSIDE every row.
// Fix: rev dirs computed in REVERSED lane space (lane j holds column 31-j):
//   - reverse scan becomes a FORWARD scan (row_shr + row_bcast15, all-DPP)
//   - edge kill at j==0 and w formula become identical to fwd chains
//   - u_rev read from LDS at 31^colx (permutation, off-chain)
//   - y of rev dirs reversed ONCE per row via ds_swizzle 0x7C1F (off-chain:
//     y feeds only the aim write, never the next row's state)
// Cross-row chain/row: nxv(2 pk_fma) -> mov_dpp -> pk_fma -> 5 fmac_dpp. No lgkm.

#define NPB 8            // images per block (one per 32-lane half, 2/wave)
#define THREADS 256
#define M_TOT 16384      // B*E
#define SCALE 0.70710678118654752f  // sqrt(1/N), N=2

typedef __attribute__((ext_vector_type(2))) float v2f;

__device__ __forceinline__ v2f v2s(float s) { return (v2f){s, s}; }
__device__ __forceinline__ v2f pfma(v2f a, v2f b, v2f c) {
    return __builtin_elementwise_fma(a, b, c);   // -> v_pk_fma_f32
}

template<int CTRL, int ROW_MASK, bool BC>
__device__ __forceinline__ float dppf(float v) {
    return __int_as_float(__builtin_amdgcn_update_dpp(
        0, __float_as_int(v), CTRL, ROW_MASK, 0xF, BC));
}
template<int CTRL, int ROW_MASK, bool BC>
__device__ __forceinline__ v2f dpp2(v2f v) {
    v2f r;
    r.x = dppf<CTRL, ROW_MASK, BC>(v.x);
    r.y = dppf<CTRL, ROW_MASK, BC>(v.y);
    return r;
}
// full 32-lane reversal within each 32-half: bit-mode xor_mask=0x1F
__device__ __forceinline__ float swzrev(float v) {
    return __int_as_float(__builtin_amdgcn_ds_swizzle(__float_as_int(v), 0x7C1F));
}

__device__ __forceinline__ float sigm(float v) { return 1.0f / (1.0f + __expf(-v)); }

struct DirP2 {
    v2f a1, p2, p4, p8, w;        // scan coefficients
    v2f a2z, ab, a3, a4, b1, b2, a3b1, c1s, c2s;
    float k00;
};

// Unified init: ALL dirs use forward-scan form now (rev dirs are in reversed
// lane space, where their scan is a forward scan; edge kill lands at j==0 for
// both: fwd kills column 0, rev kills column 31 which sits at lane 0).
__device__ __forceinline__ void dir_init2(DirP2& P, int h, int j,
    const float* __restrict__ A1p, const float* __restrict__ A2p,
    const float* __restrict__ A3p, const float* __restrict__ A4p,
    const float* __restrict__ B1p, const float* __restrict__ B2p,
    const float* __restrict__ C1p, const float* __restrict__ C2p)
{
    float2 a1r = *(const float2*)(A1p + 2 * h);
    float2 a2r = *(const float2*)(A2p + 2 * h);
    float2 a3r = *(const float2*)(A3p + 2 * h);
    float2 a4r = *(const float2*)(A4p + 2 * h);
    float2 b1r = *(const float2*)(B1p + 2 * h);
    float2 b2r = *(const float2*)(B2p + 2 * h);
    float2 c1r = *(const float2*)(C1p + 2 * h);
    float2 c2r = *(const float2*)(C2p + 2 * h);
    float a1v0 = sigm(a1r.x), a1v1 = sigm(a1r.y);
    P.a1 = (v2f){a1v0, a1v1};
    P.p2 = P.a1 * P.a1; P.p4 = P.p2 * P.p2; P.p8 = P.p4 * P.p4;
    P.a3 = (v2f){sigm(a3r.x), sigm(a3r.y)};
    P.a4 = (v2f){sigm(a4r.x), sigm(a4r.y)};
    P.b1 = (v2f){sigm(b1r.x), sigm(b1r.y)};
    P.b2 = (v2f){sigm(b2r.x), sigm(b2r.y)};
    P.a3b1 = P.a3 * P.b1;
    P.c1s = (v2f){SCALE * c1r.x, SCALE * c1r.y};
    P.c2s = (v2f){SCALE * c2r.x, SCALE * c2r.y};
    v2f kk = P.c1s * P.b1 + P.c2s * P.b2;
    P.k00 = kk.x + kk.y;
    // edge kill at j==0 (kills column-0 leak for fwd dirs, column-31 leak for
    // reversed-space rev dirs, AND the wave_shr cross-half leak for both)
    const bool edge = (j == 0);
    v2f a2n = (v2f){sigm(a2r.x), sigm(a2r.y)};
    P.a2z = edge ? (v2f){0.f, 0.f} : a2n;
    P.ab  = P.a2z * P.b2;
    float e = (float)((j & 15) + 1);
    P.w = (v2f){__powf(a1v0, e), __powf(a1v1, e)};
}

// recurrence front-end (forward form, used by ALL dirs): produce nxv, ncx and
// the two scan inputs d, e. Caller feeds u (or u_rev) as u2/up2.
__device__ __forceinline__ void dir_pre(const DirP2& P, v2f u2, v2f up2,
    v2f xh, v2f xv, v2f cx, v2f& nxv, v2f& ncx, v2f& d, v2f& e)
{
    v2f b2u = P.b2 * u2;
    nxv = pfma(P.a3, xh, pfma(P.a4, xv, b2u));
    ncx = pfma(P.a3b1, up2, pfma(P.a4, cx, b2u));
    v2f xl  = dpp2<0x138, 0xF, true>(nxv);   // wave_shr:1 (neighbor lane j-1)
    v2f ul2 = dpp2<0x138, 0xF, true>(u2);
    v2f b1u = P.b1 * u2;
    d = pfma(P.a2z, xl, b1u);
    e = pfma(P.ab, ul2, b1u);
}

// dot + state update
__device__ __forceinline__ float dir_post(const DirP2& P, v2f nh, v2f rh,
    v2f nxv, v2f ncx, v2f& xh, v2f& xv, v2f& cx)
{
    v2f acc = pfma(P.c1s, nh + rh, P.c2s * (nxv + ncx));
    xh = nh; xv = nxv; cx = ncx;
    return acc.x + acc.y;
}

// 8 interleaved FORWARD scan chains, 5 stages each, all v_fmac_f32_dpp.
// f* = dir F ({d,e} x {n0,n1}), r* = dir R in reversed lane space.
// 8-wide interleave covers the DPP read-after-VALU-write hazard.
__device__ __forceinline__ void scan8(
    float& f0, float& f1, float& f2, float& f3,
    float& r0, float& r1, float& r2, float& r3,
    const DirP2& PF, const DirP2& PR)
{
    asm("s_nop 1\n\t"
        // ---- stage 1: row_shr:1 ----
        "v_fmac_f32_dpp %0, %0, %8  row_shr:1 row_mask:0xf bank_mask:0xf bound_ctrl:0\n\t"
        "v_fmac_f32_dpp %1, %1, %9  row_shr:1 row_mask:0xf bank_mask:0xf bound_ctrl:0\n\t"
        "v_fmac_f32_dpp %2, %2, %8  row_shr:1 row_mask:0xf bank_mask:0xf bound_ctrl:0\n\t"
        "v_fmac_f32_dpp %3, %3, %9  row_shr:1 row_mask:0xf bank_mask:0xf bound_ctrl:0\n\t"
        "v_fmac_f32_dpp %4, %4, %18 row_shr:1 row_mask:0xf bank_mask:0xf bound_ctrl:0\n\t"
        "v_fmac_f32_dpp %5, %5, %19 row_shr:1 row_mask:0xf bank_mask:0xf bound_ctrl:0\n\t"
        "v_fmac_f32_dpp %6, %6, %18 row_shr:1 row_mask:0xf bank_mask:0xf bound_ctrl:0\n\t"
        "v_fmac_f32_dpp %7, %7, %19 row_shr:1 row_mask:0xf bank_mask:0xf bound_ctrl:0\n\t"
        // ---- stage 2: row_shr:2 ----
        "v_fmac_f32_dpp %0, %0, %10 row_shr:2 row_mask:0xf bank_mask:0xf bound_ctrl:0\n\t"
        "v_fmac_f32_dpp %1, %1, %11 row_shr:2 row_mask:0xf bank_mask:0xf bound_ctrl:0\n\t"
        "v_fmac_f32_dpp %2, %2, %10 row_shr:2 row_mask:0xf bank_mask:0xf bound_ctrl:0\n\t"
        "v_fmac_f32_dpp %3, %3, %11 row_shr:2 row_mask:0xf bank_mask:0xf bound_ctrl:0\n\t"
        "v_fmac_f32_dpp %4, %4, %20 row_shr:2 row_mask:0xf bank_mask:0xf bound_ctrl:0\n\t"
        "v_fmac_f32_dpp %5, %5, %21 row_shr:2 row_mask:0xf bank_mask:0xf bound_ctrl:0\n\t"
        "v_fmac_f32_dpp %6, %6, %20 row_shr:2 row_mask:0xf bank_mask:0xf bound_ctrl:0\n\t"
        "v_fmac_f32_dpp %7, %7, %21 row_shr:2 row_mask:0xf bank_mask:0xf bound_ctrl:0\n\t"
        // ---- stage 3: row_shr:4 ----
        "v_fmac_f32_dpp %0, %0, %12 row_shr:4 row_mask:0xf bank_mask:0xf bound_ctrl:0\n\t"
        "v_fmac_f32_dpp %1, %1, %13 row_shr:4 row_mask:0xf bank_mask:0xf bound_ctrl:0\n\t"
        "v_fmac_f32_dpp %2, %2, %12 row_shr:4 row_mask:0xf bank_mask:0xf bound_ctrl:0\n\t"
        "v_fmac_f32_dpp %3, %3, %13 row_shr:4 row_mask:0xf bank_mask:0xf bound_ctrl:0\n\t"
        "v_fmac_f32_dpp %4, %4, %22 row_shr:4 row_mask:0xf bank_mask:0xf bound_ctrl:0\n\t"
        "v_fmac_f32_dpp %5, %5, %23 row_shr:4 row_mask:0xf bank_mask:0xf bound_ctrl:0\n\t"
        "v_fmac_f32_dpp %6, %6, %22 row_shr:4 row_mask:0xf bank_mask:0xf bound_ctrl:0\n\t"
        "v_fmac_f32_dpp %7, %7, %23 row_shr:4 row_mask:0xf bank_mask:0xf bound_ctrl:0\n\t"
        // ---- stage 4: row_shr:8 ----
        "v_fmac_f32_dpp %0, %0, %14 row_shr:8 row_mask:0xf bank_mask:0xf bound_ctrl:0\n\t"
        "v_fmac_f32_dpp %1, %1, %15 row_shr:8 row_mask:0xf bank_mask:0xf bound_ctrl:0\n\t"
        "v_fmac_f32_dpp %2, %2, %14 row_shr:8 row_mask:0xf bank_mask:0xf bound_ctrl:0\n\t"
        "v_fmac_f32_dpp %3, %3, %15 row_shr:8 row_mask:0xf bank_mask:0xf bound_ctrl:0\n\t"
        "v_fmac_f32_dpp %4, %4, %24 row_shr:8 row_mask:0xf bank_mask:0xf bound_ctrl:0\n\t"
        "v_fmac_f32_dpp %5, %5, %25 row_shr:8 row_mask:0xf bank_mask:0xf bound_ctrl:0\n\t"
        "v_fmac_f32_dpp %6, %6, %24 row_shr:8 row_mask:0xf bank_mask:0xf bound_ctrl:0\n\t"
        "v_fmac_f32_dpp %7, %7, %25 row_shr:8 row_mask:0xf bank_mask:0xf bound_ctrl:0\n\t"
        // ---- stage 5: rows 1,3 += w * lane15-of-prev-row (all 8 chains) ----
        "v_fmac_f32_dpp %0, %0, %16 row_bcast:15 row_mask:0xa bank_mask:0xf bound_ctrl:0\n\t"
        "v_fmac_f32_dpp %1, %1, %17 row_bcast:15 row_mask:0xa bank_mask:0xf bound_ctrl:0\n\t"
        "v_fmac_f32_dpp %2, %2, %16 row_bcast:15 row_mask:0xa bank_mask:0xf bound_ctrl:0\n\t"
        "v_fmac_f32_dpp %3, %3, %17 row_bcast:15 row_mask:0xa bank_mask:0xf bound_ctrl:0\n\t"
        "v_fmac_f32_dpp %4, %4, %26 row_bcast:15 row_mask:0xa bank_mask:0xf bound_ctrl:0\n\t"
        "v_fmac_f32_dpp %5, %5, %27 row_bcast:15 row_mask:0xa bank_mask:0xf bound_ctrl:0\n\t"
        "v_fmac_f32_dpp %6, %6, %26 row_bcast:15 row_mask:0xa bank_mask:0xf bound_ctrl:0\n\t"
        "v_fmac_f32_dpp %7, %7, %27 row_bcast:15 row_mask:0xa bank_mask:0xf bound_ctrl:0"
        : "+v"(f0), "+v"(f1), "+v"(f2), "+v"(f3),
          "+v"(r0), "+v"(r1), "+v"(r2), "+v"(r3)
        : "v"(PF.a1.x), "v"(PF.a1.y), "v"(PF.p2.x), "v"(PF.p2.y),
          "v"(PF.p4.x), "v"(PF.p4.y), "v"(PF.p8.x), "v"(PF.p8.y),
          "v"(PF.w.x),  "v"(PF.w.y),
          "v"(PR.a1.x), "v"(PR.a1.y), "v"(PR.p2.x), "v"(PR.p2.y),
          "v"(PR.p4.x), "v"(PR.p4.y), "v"(PR.p8.x), "v"(PR.p8.y),
          "v"(PR.w.x),  "v"(PR.w.y));
}

__global__ __launch_bounds__(THREADS) void ssm2d_kernel(
    const float* __restrict__ x,
    const float* __restrict__ A1p, const float* __restrict__ A2p,
    const float* __restrict__ A3p, const float* __restrict__ A4p,
    const float* __restrict__ B1p, const float* __restrict__ B2p,
    const float* __restrict__ C1p, const float* __restrict__ C2p,
    const float* __restrict__ omega,
    float* __restrict__ out)
{
    __shared__ __half u_lds[NPB * 1024];   // 16 KB fp16 input, XOR-swizzled
    __shared__ __half a_lds[NPB * 1024];   // 16 KB fp16 accumulator
    const int t = threadIdx.x;
    // XCD-aware remap (R6/R9 proven form)
    const int bid = blockIdx.x;
    const int m0  = ((bid & 7) * 256 + (bid >> 3)) * NPB;

    // ---- stage x into LDS (f32 -> fp16); XOR swizzle kills conflicts ----
    const int simg = t & 7;
    #pragma unroll 4
    for (int it = 0; it < 32; ++it) {
        int pix = it * 32 + (t >> 3);
        u_lds[simg * 1024 + (pix ^ (simg << 2))] =
            __float2half(x[(size_t)pix * M_TOT + (m0 + simg)]);
    }
    __syncthreads();

    const int j    = t & 31;
    const int img  = t >> 5;
    const int m    = m0 + img;
    const int hb   = m & 63;
    const int colx = j ^ (img << 2);      // per-lane swizzled column
    const int colr = 31 ^ colx;           // reversed column's swizzled index
    const __half* uim = u_lds + img * 1024;
    __half*       aim = a_lds + img * 1024;
    const float om = omega[m & 1023];

    // ============ pass A: rows ascending, d0 (fwd) + d2 (rev space) ============
    {
        DirP2 P0, P2;
        dir_init2(P0, hb,       j, A1p, A2p, A3p, A4p, B1p, B2p, C1p, C2p);
        dir_init2(P2, 128 + hb, j, A1p, A2p, A3p, A4p, B1p, B2p, C1p, C2p);
        const float omA = om - P0.k00;    // fwd k00 folds with om*u
        v2f xhF = {0,0}, xvF = {0,0}, cxF = {0,0};
        v2f xhR = {0,0}, xvR = {0,0}, cxR = {0,0};
        float up = 0.f, upr = 0.f;
        #pragma unroll 4
        for (int s = 0; s < 32; ++s) {
            float u  = __half2float(uim[s * 32 + colx]);
            float ur = __half2float(uim[s * 32 + colr]);
            v2f u2 = v2s(u), up2 = v2s(up), ur2 = v2s(ur), upr2 = v2s(upr);
            v2f nxvF, ncxF, dF, eF, nxvR, ncxR, dR, eR;
            dir_pre(P0, u2,  up2,  xhF, xvF, cxF, nxvF, ncxF, dF, eF);
            dir_pre(P2, ur2, upr2, xhR, xvR, cxR, nxvR, ncxR, dR, eR);
            float f0 = dF.x, f1 = dF.y, f2 = eF.x, f3 = eF.y;
            float r0 = dR.x, r1 = dR.y, r2 = eR.x, r3 = eR.y;
            scan8(f0, f1, f2, f3, r0, r1, r2, r3, P0, P2);
            v2f nhF = {f0, f1}, rhF = {f2, f3};
            v2f nhR = {r0, r1}, rhR = {r2, r3};
            float y0 = dir_post(P0, nhF, rhF, nxvF, ncxF, xhF, xvF, cxF);
            float y2 = dir_post(P2, nhR, rhR, nxvR, ncxR, xhR, xvR, cxR);
            y2 = fmaf(-P2.k00, ur, y2);
            float y2f = swzrev(y2);       // lane reversal (off cross-row chain)
            aim[s * 32 + colx] = __float2half(fmaf(u, omA, y0 + y2f));
            up = u; upr = ur;
        }
    }
    // ==== pass B: rows descending, d1 (fwd) + d3 (rev space) + SiLU ====
    {
        DirP2 P1, P3;
        dir_init2(P1, 64 + hb,  j, A1p, A2p, A3p, A4p, B1p, B2p, C1p, C2p);
        dir_init2(P3, 192 + hb, j, A1p, A2p, A3p, A4p, B1p, B2p, C1p, C2p);
        v2f xhF = {0,0}, xvF = {0,0}, cxF = {0,0};
        v2f xhR = {0,0}, xvR = {0,0}, cxR = {0,0};
        float up = 0.f, upr = 0.f;
        #pragma unroll 4
        for (int s = 0; s < 32; ++s) {
            int   r  = 31 - s;
            float u  = __half2float(uim[r * 32 + colx]);
            float ur = __half2float(uim[r * 32 + colr]);
            v2f u2 = v2s(u), up2 = v2s(up), ur2 = v2s(ur), upr2 = v2s(upr);
            v2f nxvF, ncxF, dF, eF, nxvR, ncxR, dR, eR;
            dir_pre(P1, u2,  up2,  xhF, xvF, cxF, nxvF, ncxF, dF, eF);
            dir_pre(P3, ur2, upr2, xhR, xvR, cxR, nxvR, ncxR, dR, eR);
            float f0 = dF.x, f1 = dF.y, f2 = eF.x, f3 = eF.y;
            float r0 = dR.x, r1 = dR.y, r2 = eR.x, r3 = eR.y;
            scan8(f0, f1, f2, f3, r0, r1, r2, r3, P1, P3);
            v2f nhF = {f0, f1}, rhF = {f2, f3};
            v2f nhR = {r0, r1}, rhR = {r2, r3};
            float y1 = dir_post(P1, nhF, rhF, nxvF, ncxF, xhF, xvF, cxF);
            float y3 = dir_post(P3, nhR, rhR, nxvR, ncxR, xhR, xvR, cxR);
            y3 = fmaf(-P3.k00, ur, y3);
            float y3f = swzrev(y3);       // lane reversal (off cross-row chain)
            float z  = __half2float(aim[r * 32 + colx]) + y1 + y3f;
            z = fmaf(u, -P1.k00, z);
            float sg = 1.0f / (1.0f + __expf(-z));
            aim[r * 32 + colx] = __float2half(z * sg);   // in-place finalize
            up = u; upr = ur;
        }
    }
    __syncthreads();

    // ---- coalesced store-out (fp16 -> f32) ----
    #pragma unroll 4
    for (int it = 0; it < 32; ++it) {
        int pix = it * 32 + (t >> 3);
        out[(size_t)pix * M_TOT + (m0 + simg)] =
            __half2float(a_lds[simg * 1024 + (pix ^ (simg << 2))]);
    }
}

extern "C" void kernel_launch(void* const* d_in, const int* in_sizes, int n_in,
                              void* d_out, int out_size, void* d_ws, size_t ws_size,
                              hipStream_t stream) {
    const float* x  = (const float*)d_in[0];
    const float* A1 = (const float*)d_in[1];
    const float* A2 = (const float*)d_in[2];
    const float* A3 = (const float*)d_in[3];
    const float* A4 = (const float*)d_in[4];
    const float* B1 = (const float*)d_in[5];
    const float* B2 = (const float*)d_in[6];
    const float* C1 = (const float*)d_in[7];
    const float* C2 = (const float*)d_in[8];
    const float* om = (const float*)d_in[9];
    float* out = (float*)d_out;
    hipLaunchKernelGGL(ssm2d_kernel, dim3(M_TOT / NPB), dim3(THREADS), 0, stream,
                       x, A1, A2, A3, A4, B1, B2, C1, C2, om, out);
}

// Round 6
// 210.694 us; speedup vs baseline: 1.1276x; 1.0779x over previous
//
#include <hip/hip_runtime.h>
#include <hip/hip_fp16.h>

// TwoDimensionalSSM via direct 2D recurrence. Round 12: packed-fp16 inner loop.
// R11 post-mortem: removing ds_swizzle from the cross-row chain was neutral
// (143->140us) -> latency theories exhausted. Busy-time tracks dur across all
// rounds (~20% idle residual) at ~5.6cyc/inst vs 2cyc SIMD-32 issue: the only
// class abundant enough is DPP (~48/iter). Theory: wave64 cross-lane DPP is
// multi-cycle on SIMD-32. Fix: halve DPP count via v_pk_fmac_f16_dpp (VOP2 ->
// DPP-capable packed-half FMAC): each scan chain carries (n0,n1) in ONE half2
// reg -> 40 scan DPP -> 20, dir_pre movs 8 -> 4. All recurrence math half2
// (v_pk_fma_f16), output dot via v_dot2_f32_f16 (f32 accumulate). u consumed
// as f16 straight from LDS (no cvt+splat). Static ~90 -> ~58 VALU/iter.
// Precision: fp16 states add ~1e-3 rel/row with geometric decay; dots in f32.
// Structure (staging, swizzles, reversed-lane rev dirs, edge kill): R11 proven.

#define NPB 8            // images per block (one per 32-lane half, 2/wave)
#define THREADS 256
#define M_TOT 16384      // B*E
#define SCALE 0.70710678118654752f  // sqrt(1/N), N=2

typedef __attribute__((ext_vector_type(2))) _Float16 v2h;

__device__ __forceinline__ unsigned h2u(v2h v) { return __builtin_bit_cast(unsigned, v); }
__device__ __forceinline__ v2h u2h(unsigned v) { return __builtin_bit_cast(v2h, v); }
__device__ __forceinline__ v2h hfma2v(v2h a, v2h b, v2h c) {
    return __builtin_elementwise_fma(a, b, c);   // -> v_pk_fma_f16
}
__device__ __forceinline__ v2h cvt2(float x, float y) {
    return (v2h){(_Float16)x, (_Float16)y};
}

template<int CTRL>
__device__ __forceinline__ v2h dpph(v2h v) {   // packed mov_dpp (whole 32b reg)
    return u2h((unsigned)__builtin_amdgcn_update_dpp(
        0, (int)h2u(v), CTRL, 0xF, 0xF, true));
}
// full 32-lane reversal within each 32-half: bit-mode xor_mask=0x1F
__device__ __forceinline__ float swzrev(float v) {
    return __int_as_float(__builtin_amdgcn_ds_swizzle(__float_as_int(v), 0x7C1F));
}
__device__ __forceinline__ float sigm(float v) { return 1.0f / (1.0f + __expf(-v)); }

struct DirPH {
    v2h a1, p2, p4, p8, w;            // scan coefficients (n0,n1 packed)
    v2h a2z, ab, a3, a4, b1, b2, a3b1, c1, c2;
    float k00;
};

// Unified forward-scan init (rev dirs run in reversed lane space; edge kill at
// j==0 covers fwd col-0 leak, rev col-31 leak, and the wave_shr cross-half leak)
__device__ __forceinline__ void dir_init_h(DirPH& P, int h, int j,
    const float* __restrict__ A1p, const float* __restrict__ A2p,
    const float* __restrict__ A3p, const float* __restrict__ A4p,
    const float* __restrict__ B1p, const float* __restrict__ B2p,
    const float* __restrict__ C1p, const float* __restrict__ C2p)
{
    float2 a1r = *(const float2*)(A1p + 2 * h);
    float2 a2r = *(const float2*)(A2p + 2 * h);
    float2 a3r = *(const float2*)(A3p + 2 * h);
    float2 a4r = *(const float2*)(A4p + 2 * h);
    float2 b1r = *(const float2*)(B1p + 2 * h);
    float2 b2r = *(const float2*)(B2p + 2 * h);
    float2 c1r = *(const float2*)(C1p + 2 * h);
    float2 c2r = *(const float2*)(C2p + 2 * h);
    float a1v0 = sigm(a1r.x), a1v1 = sigm(a1r.y);
    float p2v0 = a1v0 * a1v0, p2v1 = a1v1 * a1v1;
    float p4v0 = p2v0 * p2v0, p4v1 = p2v1 * p2v1;
    float p8v0 = p4v0 * p4v0, p8v1 = p4v1 * p4v1;
    float a3v0 = sigm(a3r.x), a3v1 = sigm(a3r.y);
    float a4v0 = sigm(a4r.x), a4v1 = sigm(a4r.y);
    float b1v0 = sigm(b1r.x), b1v1 = sigm(b1r.y);
    float b2v0 = sigm(b2r.x), b2v1 = sigm(b2r.y);
    float c1v0 = SCALE * c1r.x, c1v1 = SCALE * c1r.y;
    float c2v0 = SCALE * c2r.x, c2v1 = SCALE * c2r.y;
    P.a1 = cvt2(a1v0, a1v1); P.p2 = cvt2(p2v0, p2v1);
    P.p4 = cvt2(p4v0, p4v1); P.p8 = cvt2(p8v0, p8v1);
    P.a3 = cvt2(a3v0, a3v1); P.a4 = cvt2(a4v0, a4v1);
    P.b1 = cvt2(b1v0, b1v1); P.b2 = cvt2(b2v0, b2v1);
    P.a3b1 = cvt2(a3v0 * b1v0, a3v1 * b1v1);
    P.c1 = cvt2(c1v0, c1v1); P.c2 = cvt2(c2v0, c2v1);
    P.k00 = c1v0 * b1v0 + c1v1 * b1v1 + c2v0 * b2v0 + c2v1 * b2v1;
    const bool edge = (j == 0);
    float z0 = edge ? 0.f : sigm(a2r.x);
    float z1 = edge ? 0.f : sigm(a2r.y);
    P.a2z = cvt2(z0, z1);
    P.ab  = cvt2(z0 * b2v0, z1 * b2v1);
    float e = (float)((j & 15) + 1);
    P.w = cvt2(__powf(a1v0, e), __powf(a1v1, e));
}

// recurrence front-end (forward form, all dirs): nxv, ncx and scan inputs d, e
__device__ __forceinline__ void dir_pre_h(const DirPH& P, v2h u2, v2h up2,
    v2h xh, v2h xv, v2h cx, v2h& nxv, v2h& ncx, v2h& d, v2h& e)
{
    v2h b2u = P.b2 * u2;
    nxv = hfma2v(P.a3, xh, hfma2v(P.a4, xv, b2u));
    ncx = hfma2v(P.a3b1, up2, hfma2v(P.a4, cx, b2u));
    v2h xl = dpph<0x138>(nxv);    // wave_shr:1 (neighbor lane j-1), packed
    v2h ul = dpph<0x138>(u2);
    v2h b1u = P.b1 * u2;
    d = hfma2v(P.a2z, xl, b1u);
    e = hfma2v(P.ab, ul, b1u);
}

// dot (f32 accumulate via v_dot2_f32_f16) + state update
__device__ __forceinline__ float dir_post_h(const DirPH& P, v2h nh, v2h rh,
    v2h nxv, v2h ncx, v2h& xh, v2h& xv, v2h& cx, float base)
{
    v2h s1 = nh + rh;
    v2h s2 = nxv + ncx;
    float y = __builtin_amdgcn_fdot2(P.c1, s1,
              __builtin_amdgcn_fdot2(P.c2, s2, base, false), false);
    xh = nh; xv = nxv; cx = ncx;
    return y;
}

// 4 packed forward scan chains, 5 stages, ONE v_pk_fmac_f16_dpp per stage per
// chain. 4-wide interleave: each chain's next stage is 3 instrs after its
// producer (>= 2 DPP wait states); s_nop 1 guards the asm entry edge.
__device__ __forceinline__ void scan4h(
    unsigned& f0, unsigned& f1, unsigned& r0, unsigned& r1,
    const DirPH& PF, const DirPH& PR)
{
    asm("s_nop 1\n\t"
        // ---- stage 1: row_shr:1 ----
        "v_pk_fmac_f16_dpp %0, %0, %4  row_shr:1 row_mask:0xf bank_mask:0xf bound_ctrl:0\n\t"
        "v_pk_fmac_f16_dpp %1, %1, %4  row_shr:1 row_mask:0xf bank_mask:0xf bound_ctrl:0\n\t"
        "v_pk_fmac_f16_dpp %2, %2, %9  row_shr:1 row_mask:0xf bank_mask:0xf bound_ctrl:0\n\t"
        "v_pk_fmac_f16_dpp %3, %3, %9  row_shr:1 row_mask:0xf bank_mask:0xf bound_ctrl:0\n\t"
        // ---- stage 2: row_shr:2 ----
        "v_pk_fmac_f16_dpp %0, %0, %5  row_shr:2 row_mask:0xf bank_mask:0xf bound_ctrl:0\n\t"
        "v_pk_fmac_f16_dpp %1, %1, %5  row_shr:2 row_mask:0xf bank_mask:0xf bound_ctrl:0\n\t"
        "v_pk_fmac_f16_dpp %2, %2, %10 row_shr:2 row_mask:0xf bank_mask:0xf bound_ctrl:0\n\t"
        "v_pk_fmac_f16_dpp %3, %3, %10 row_shr:2 row_mask:0xf bank_mask:0xf bound_ctrl:0\n\t"
        // ---- stage 3: row_shr:4 ----
        "v_pk_fmac_f16_dpp %0, %0, %6  row_shr:4 row_mask:0xf bank_mask:0xf bound_ctrl:0\n\t"
        "v_pk_fmac_f16_dpp %1, %1, %6  row_shr:4 row_mask:0xf bank_mask:0xf bound_ctrl:0\n\t"
        "v_pk_fmac_f16_dpp %2, %2, %11 row_shr:4 row_mask:0xf bank_mask:0xf bound_ctrl:0\n\t"
        "v_pk_fmac_f16_dpp %3, %3, %11 row_shr:4 row_mask:0xf bank_mask:0xf bound_ctrl:0\n\t"
        // ---- stage 4: row_shr:8 ----
        "v_pk_fmac_f16_dpp %0, %0, %7  row_shr:8 row_mask:0xf bank_mask:0xf bound_ctrl:0\n\t"
        "v_pk_fmac_f16_dpp %1, %1, %7  row_shr:8 row_mask:0xf bank_mask:0xf bound_ctrl:0\n\t"
        "v_pk_fmac_f16_dpp %2, %2, %12 row_shr:8 row_mask:0xf bank_mask:0xf bound_ctrl:0\n\t"
        "v_pk_fmac_f16_dpp %3, %3, %12 row_shr:8 row_mask:0xf bank_mask:0xf bound_ctrl:0\n\t"
        // ---- stage 5: rows 1,3 += w * lane15-of-prev-row ----
        "v_pk_fmac_f16_dpp %0, %0, %8  row_bcast:15 row_mask:0xa bank_mask:0xf bound_ctrl:0\n\t"
        "v_pk_fmac_f16_dpp %1, %1, %8  row_bcast:15 row_mask:0xa bank_mask:0xf bound_ctrl:0\n\t"
        "v_pk_fmac_f16_dpp %2, %2, %13 row_bcast:15 row_mask:0xa bank_mask:0xf bound_ctrl:0\n\t"
        "v_pk_fmac_f16_dpp %3, %3, %13 row_bcast:15 row_mask:0xa bank_mask:0xf bound_ctrl:0"
        : "+v"(f0), "+v"(f1), "+v"(r0), "+v"(r1)
        : "v"(h2u(PF.a1)), "v"(h2u(PF.p2)), "v"(h2u(PF.p4)),
          "v"(h2u(PF.p8)), "v"(h2u(PF.w)),
          "v"(h2u(PR.a1)), "v"(h2u(PR.p2)), "v"(h2u(PR.p4)),
          "v"(h2u(PR.p8)), "v"(h2u(PR.w)));
}

__global__ __launch_bounds__(THREADS) void ssm2d_kernel(
    const float* __restrict__ x,
    const float* __restrict__ A1p, const float* __restrict__ A2p,
    const float* __restrict__ A3p, const float* __restrict__ A4p,
    const float* __restrict__ B1p, const float* __restrict__ B2p,
    const float* __restrict__ C1p, const float* __restrict__ C2p,
    const float* __restrict__ omega,
    float* __restrict__ out)
{
    __shared__ _Float16 u_lds[NPB * 1024];   // 16 KB fp16 input, XOR-swizzled
    __shared__ _Float16 a_lds[NPB * 1024];   // 16 KB fp16 accumulator
    const int t = threadIdx.x;
    // XCD-aware remap (proven form)
    const int bid = blockIdx.x;
    const int m0  = ((bid & 7) * 256 + (bid >> 3)) * NPB;

    // ---- stage x into LDS (f32 -> fp16); XOR swizzle kills conflicts ----
    const int simg = t & 7;
    #pragma unroll 4
    for (int it = 0; it < 32; ++it) {
        int pix = it * 32 + (t >> 3);
        u_lds[simg * 1024 + (pix ^ (simg << 2))] =
            (_Float16)x[(size_t)pix * M_TOT + (m0 + simg)];
    }
    __syncthreads();

    const int j    = t & 31;
    const int img  = t >> 5;
    const int m    = m0 + img;
    const int hb   = m & 63;
    const int colx = j ^ (img << 2);      // per-lane swizzled column
    const int colr = 31 ^ colx;           // reversed column's swizzled index
    const _Float16* uim = u_lds + img * 1024;
    _Float16*       aim = a_lds + img * 1024;
    const float om = omega[m & 1023];

    // ============ pass A: rows ascending, d0 (fwd) + d2 (rev space) ============
    {
        DirPH P0, P2;
        dir_init_h(P0, hb,       j, A1p, A2p, A3p, A4p, B1p, B2p, C1p, C2p);
        dir_init_h(P2, 128 + hb, j, A1p, A2p, A3p, A4p, B1p, B2p, C1p, C2p);
        const float omA = om - P0.k00;    // fwd k00 folds with om*u
        v2h xhF = {0,0}, xvF = {0,0}, cxF = {0,0};
        v2h xhR = {0,0}, xvR = {0,0}, cxR = {0,0};
        v2h up2 = {0,0}, upr2 = {0,0};
        #pragma unroll 4
        for (int s = 0; s < 32; ++s) {
            _Float16 uh  = uim[s * 32 + colx];
            _Float16 urh = uim[s * 32 + colr];
            float uf = (float)uh, urf = (float)urh;
            v2h u2  = (v2h){uh, uh};
            v2h ur2 = (v2h){urh, urh};
            v2h nxvF, ncxF, dF, eF, nxvR, ncxR, dR, eR;
            dir_pre_h(P0, u2,  up2,  xhF, xvF, cxF, nxvF, ncxF, dF, eF);
            dir_pre_h(P2, ur2, upr2, xhR, xvR, cxR, nxvR, ncxR, dR, eR);
            unsigned f0 = h2u(dF), f1 = h2u(eF), r0 = h2u(dR), r1 = h2u(eR);
            scan4h(f0, f1, r0, r1, P0, P2);
            float y0 = dir_post_h(P0, u2h(f0), u2h(f1), nxvF, ncxF,
                                  xhF, xvF, cxF, 0.f);
            float y2 = dir_post_h(P2, u2h(r0), u2h(r1), nxvR, ncxR,
                                  xhR, xvR, cxR, -P2.k00 * urf);
            float y2f = swzrev(y2);       // lane reversal (off cross-row chain)
            aim[s * 32 + colx] = (_Float16)fmaf(uf, omA, y0 + y2f);
            up2 = u2; upr2 = ur2;
        }
    }
    // ==== pass B: rows descending, d1 (fwd) + d3 (rev space) + SiLU ====
    {
        DirPH P1, P3;
        dir_init_h(P1, 64 + hb,  j, A1p, A2p, A3p, A4p, B1p, B2p, C1p, C2p);
        dir_init_h(P3, 192 + hb, j, A1p, A2p, A3p, A4p, B1p, B2p, C1p, C2p);
        v2h xhF = {0,0}, xvF = {0,0}, cxF = {0,0};
        v2h xhR = {0,0}, xvR = {0,0}, cxR = {0,0};
        v2h up2 = {0,0}, upr2 = {0,0};
        #pragma unroll 4
        for (int s = 0; s < 32; ++s) {
            int   r   = 31 - s;
            _Float16 uh  = uim[r * 32 + colx];
            _Float16 urh = uim[r * 32 + colr];
            float uf = (float)uh, urf = (float)urh;
            v2h u2  = (v2h){uh, uh};
            v2h ur2 = (v2h){urh, urh};
            v2h nxvF, ncxF, dF, eF, nxvR, ncxR, dR, eR;
            dir_pre_h(P1, u2,  up2,  xhF, xvF, cxF, nxvF, ncxF, dF, eF);
            dir_pre_h(P3, ur2, upr2, xhR, xvR, cxR, nxvR, ncxR, dR, eR);
            unsigned f0 = h2u(dF), f1 = h2u(eF), r0 = h2u(dR), r1 = h2u(eR);
            scan4h(f0, f1, r0, r1, P1, P3);
            float y1 = dir_post_h(P1, u2h(f0), u2h(f1), nxvF, ncxF,
                                  xhF, xvF, cxF, 0.f);
            float y3 = dir_post_h(P3, u2h(r0), u2h(r1), nxvR, ncxR,
                                  xhR, xvR, cxR, -P3.k00 * urf);
            float y3f = swzrev(y3);       // lane reversal (off cross-row chain)
            float z  = (float)aim[r * 32 + colx] + y1 + y3f;
            z = fmaf(uf, -P1.k00, z);
            float sg = 1.0f / (1.0f + __expf(-z));
            aim[r * 32 + colx] = (_Float16)(z * sg);   // in-place finalize
            up2 = u2; upr2 = ur2;
        }
    }
    __syncthreads();

    // ---- coalesced store-out (fp16 -> f32) ----
    #pragma unroll 4
    for (int it = 0; it < 32; ++it) {
        int pix = it * 32 + (t >> 3);
        out[(size_t)pix * M_TOT + (m0 + simg)] =
            (float)a_lds[simg * 1024 + (pix ^ (simg << 2))];
    }
}

extern "C" void kernel_launch(void* const* d_in, const int* in_sizes, int n_in,
                              void* d_out, int out_size, void* d_ws, size_t ws_size,
                              hipStream_t stream) {
    const float* x  = (const float*)d_in[0];
    const float* A1 = (const float*)d_in[1];
    const float* A2 = (const float*)d_in[2];
    const float* A3 = (const float*)d_in[3];
    const float* A4 = (const float*)d_in[4];
    const float* B1 = (const float*)d_in[5];
    const float* B2 = (const float*)d_in[6];
    const float* C1 = (const float*)d_in[7];
    const float* C2 = (const float*)d_in[8];
    const float* om = (const float*)d_in[9];
    float* out = (float*)d_out;
    hipLaunchKernelGGL(ssm2d_kernel, dim3(M_TOT / NPB), dim3(THREADS), 0, stream,
                       x, A1, A2, A3, A4, B1, B2, C1, C2, om, out);
}

// Round 7
// 204.863 us; speedup vs baseline: 1.1597x; 1.0285x over previous
//
#include <hip/hip_runtime.h>
#include <hip/hip_fp16.h>

// TwoDimensionalSSM via direct 2D recurrence. Round 13: pass-split across
// waves. R12 post-mortem: packed-fp16 loop won (140->122us, VGPR 48) and
// exposed the structure dur ~= busy(insts) + ~27us FIXED idle (idle constant
// across R11/R12 while busy fell with static count). Theory: idle = serial
// phase structure (64-iter chain/wave + staging head + store tail), not
// instructions. Fix: pass B == pass A on row-flipped u (31-s == s^31), so run
// each (image, pass) on its own 32-lane half: 512 threads, 16 half-slots =
// 8 images x 2 passes, each a UNIFIED 32-iter loop (flip = XOR mask on row
// index; k00/omega folded into one per-lane constant). Partials -> 32KB LDS;
// combine+SiLU fused into the store loop. Per-wave serial work halves, wave
// count doubles, pass-B aim-read disappears. Mixed flip in a wave is safe:
// the only cross-half DPP leak (wave_shr:1) is killed by the j==0 edge mask.
// Inner math identical to R12 (pk_fma_f16 / pk_fmac_f16_dpp / fdot2).

#define NPB 8            // images per block
#define THREADS 512      // 8 waves; half-slot (t>>5) = (img<<1)|flip
#define M_TOT 16384      // B*E
#define SCALE 0.70710678118654752f  // sqrt(1/N), N=2

typedef __attribute__((ext_vector_type(2))) _Float16 v2h;

__device__ __forceinline__ unsigned h2u(v2h v) { return __builtin_bit_cast(unsigned, v); }
__device__ __forceinline__ v2h u2h(unsigned v) { return __builtin_bit_cast(v2h, v); }
__device__ __forceinline__ v2h hfma2v(v2h a, v2h b, v2h c) {
    return __builtin_elementwise_fma(a, b, c);   // -> v_pk_fma_f16
}
__device__ __forceinline__ v2h cvt2(float x, float y) {
    return (v2h){(_Float16)x, (_Float16)y};
}

template<int CTRL>
__device__ __forceinline__ v2h dpph(v2h v) {   // packed mov_dpp (whole 32b reg)
    return u2h((unsigned)__builtin_amdgcn_update_dpp(
        0, (int)h2u(v), CTRL, 0xF, 0xF, true));
}
// full 32-lane reversal within each 32-half: bit-mode xor_mask=0x1F
__device__ __forceinline__ float swzrev(float v) {
    return __int_as_float(__builtin_amdgcn_ds_swizzle(__float_as_int(v), 0x7C1F));
}
__device__ __forceinline__ float sigm(float v) { return 1.0f / (1.0f + __expf(-v)); }

struct DirPH {
    v2h a1, p2, p4, p8, w;            // scan coefficients (n0,n1 packed)
    v2h a2z, ab, a3, a4, b1, b2, a3b1, c1, c2;
    float k00;
};

// Unified forward-scan init (rev dirs run in reversed lane space; edge kill at
// j==0 covers fwd col-0 leak, rev col-31 leak, and the wave_shr cross-half leak)
__device__ __forceinline__ void dir_init_h(DirPH& P, int h, int j,
    const float* __restrict__ A1p, const float* __restrict__ A2p,
    const float* __restrict__ A3p, const float* __restrict__ A4p,
    const float* __restrict__ B1p, const float* __restrict__ B2p,
    const float* __restrict__ C1p, const float* __restrict__ C2p)
{
    float2 a1r = *(const float2*)(A1p + 2 * h);
    float2 a2r = *(const float2*)(A2p + 2 * h);
    float2 a3r = *(const float2*)(A3p + 2 * h);
    float2 a4r = *(const float2*)(A4p + 2 * h);
    float2 b1r = *(const float2*)(B1p + 2 * h);
    float2 b2r = *(const float2*)(B2p + 2 * h);
    float2 c1r = *(const float2*)(C1p + 2 * h);
    float2 c2r = *(const float2*)(C2p + 2 * h);
    float a1v0 = sigm(a1r.x), a1v1 = sigm(a1r.y);
    float p2v0 = a1v0 * a1v0, p2v1 = a1v1 * a1v1;
    float p4v0 = p2v0 * p2v0, p4v1 = p2v1 * p2v1;
    float p8v0 = p4v0 * p4v0, p8v1 = p4v1 * p4v1;
    float a3v0 = sigm(a3r.x), a3v1 = sigm(a3r.y);
    float a4v0 = sigm(a4r.x), a4v1 = sigm(a4r.y);
    float b1v0 = sigm(b1r.x), b1v1 = sigm(b1r.y);
    float b2v0 = sigm(b2r.x), b2v1 = sigm(b2r.y);
    float c1v0 = SCALE * c1r.x, c1v1 = SCALE * c1r.y;
    float c2v0 = SCALE * c2r.x, c2v1 = SCALE * c2r.y;
    P.a1 = cvt2(a1v0, a1v1); P.p2 = cvt2(p2v0, p2v1);
    P.p4 = cvt2(p4v0, p4v1); P.p8 = cvt2(p8v0, p8v1);
    P.a3 = cvt2(a3v0, a3v1); P.a4 = cvt2(a4v0, a4v1);
    P.b1 = cvt2(b1v0, b1v1); P.b2 = cvt2(b2v0, b2v1);
    P.a3b1 = cvt2(a3v0 * b1v0, a3v1 * b1v1);
    P.c1 = cvt2(c1v0, c1v1); P.c2 = cvt2(c2v0, c2v1);
    P.k00 = c1v0 * b1v0 + c1v1 * b1v1 + c2v0 * b2v0 + c2v1 * b2v1;
    const bool edge = (j == 0);
    float z0 = edge ? 0.f : sigm(a2r.x);
    float z1 = edge ? 0.f : sigm(a2r.y);
    P.a2z = cvt2(z0, z1);
    P.ab  = cvt2(z0 * b2v0, z1 * b2v1);
    float e = (float)((j & 15) + 1);
    P.w = cvt2(__powf(a1v0, e), __powf(a1v1, e));
}

// recurrence front-end (forward form, all dirs): nxv, ncx and scan inputs d, e
__device__ __forceinline__ void dir_pre_h(const DirPH& P, v2h u2, v2h up2,
    v2h xh, v2h xv, v2h cx, v2h& nxv, v2h& ncx, v2h& d, v2h& e)
{
    v2h b2u = P.b2 * u2;
    nxv = hfma2v(P.a3, xh, hfma2v(P.a4, xv, b2u));
    ncx = hfma2v(P.a3b1, up2, hfma2v(P.a4, cx, b2u));
    v2h xl = dpph<0x138>(nxv);    // wave_shr:1 (neighbor lane j-1), packed
    v2h ul = dpph<0x138>(u2);
    v2h b1u = P.b1 * u2;
    d = hfma2v(P.a2z, xl, b1u);
    e = hfma2v(P.ab, ul, b1u);
}

// dot (f32 accumulate via v_dot2_f32_f16) + state update
__device__ __forceinline__ float dir_post_h(const DirPH& P, v2h nh, v2h rh,
    v2h nxv, v2h ncx, v2h& xh, v2h& xv, v2h& cx, float base)
{
    v2h s1 = nh + rh;
    v2h s2 = nxv + ncx;
    float y = __builtin_amdgcn_fdot2(P.c1, s1,
              __builtin_amdgcn_fdot2(P.c2, s2, base, false), false);
    xh = nh; xv = nxv; cx = ncx;
    return y;
}

// 4 packed forward scan chains, 5 stages, ONE v_pk_fmac_f16_dpp per stage per
// chain. 4-wide interleave covers DPP wait states; s_nop 1 guards entry.
__device__ __forceinline__ void scan4h(
    unsigned& f0, unsigned& f1, unsigned& r0, unsigned& r1,
    const DirPH& PF, const DirPH& PR)
{
    asm("s_nop 1\n\t"
        // ---- stage 1: row_shr:1 ----
        "v_pk_fmac_f16_dpp %0, %0, %4  row_shr:1 row_mask:0xf bank_mask:0xf bound_ctrl:0\n\t"
        "v_pk_fmac_f16_dpp %1, %1, %4  row_shr:1 row_mask:0xf bank_mask:0xf bound_ctrl:0\n\t"
        "v_pk_fmac_f16_dpp %2, %2, %9  row_shr:1 row_mask:0xf bank_mask:0xf bound_ctrl:0\n\t"
        "v_pk_fmac_f16_dpp %3, %3, %9  row_shr:1 row_mask:0xf bank_mask:0xf bound_ctrl:0\n\t"
        // ---- stage 2: row_shr:2 ----
        "v_pk_fmac_f16_dpp %0, %0, %5  row_shr:2 row_mask:0xf bank_mask:0xf bound_ctrl:0\n\t"
        "v_pk_fmac_f16_dpp %1, %1, %5  row_shr:2 row_mask:0xf bank_mask:0xf bound_ctrl:0\n\t"
        "v_pk_fmac_f16_dpp %2, %2, %10 row_shr:2 row_mask:0xf bank_mask:0xf bound_ctrl:0\n\t"
        "v_pk_fmac_f16_dpp %3, %3, %10 row_shr:2 row_mask:0xf bank_mask:0xf bound_ctrl:0\n\t"
        // ---- stage 3: row_shr:4 ----
        "v_pk_fmac_f16_dpp %0, %0, %6  row_shr:4 row_mask:0xf bank_mask:0xf bound_ctrl:0\n\t"
        "v_pk_fmac_f16_dpp %1, %1, %6  row_shr:4 row_mask:0xf bank_mask:0xf bound_ctrl:0\n\t"
        "v_pk_fmac_f16_dpp %2, %2, %11 row_shr:4 row_mask:0xf bank_mask:0xf bound_ctrl:0\n\t"
        "v_pk_fmac_f16_dpp %3, %3, %11 row_shr:4 row_mask:0xf bank_mask:0xf bound_ctrl:0\n\t"
        // ---- stage 4: row_shr:8 ----
        "v_pk_fmac_f16_dpp %0, %0, %7  row_shr:8 row_mask:0xf bank_mask:0xf bound_ctrl:0\n\t"
        "v_pk_fmac_f16_dpp %1, %1, %7  row_shr:8 row_mask:0xf bank_mask:0xf bound_ctrl:0\n\t"
        "v_pk_fmac_f16_dpp %2, %2, %12 row_shr:8 row_mask:0xf bank_mask:0xf bound_ctrl:0\n\t"
        "v_pk_fmac_f16_dpp %3, %3, %12 row_shr:8 row_mask:0xf bank_mask:0xf bound_ctrl:0\n\t"
        // ---- stage 5: rows 1,3 += w * lane15-of-prev-row ----
        "v_pk_fmac_f16_dpp %0, %0, %8  row_bcast:15 row_mask:0xa bank_mask:0xf bound_ctrl:0\n\t"
        "v_pk_fmac_f16_dpp %1, %1, %8  row_bcast:15 row_mask:0xa bank_mask:0xf bound_ctrl:0\n\t"
        "v_pk_fmac_f16_dpp %2, %2, %13 row_bcast:15 row_mask:0xa bank_mask:0xf bound_ctrl:0\n\t"
        "v_pk_fmac_f16_dpp %3, %3, %13 row_bcast:15 row_mask:0xa bank_mask:0xf bound_ctrl:0"
        : "+v"(f0), "+v"(f1), "+v"(r0), "+v"(r1)
        : "v"(h2u(PF.a1)), "v"(h2u(PF.p2)), "v"(h2u(PF.p4)),
          "v"(h2u(PF.p8)), "v"(h2u(PF.w)),
          "v"(h2u(PR.a1)), "v"(h2u(PR.p2)), "v"(h2u(PR.p4)),
          "v"(h2u(PR.p8)), "v"(h2u(PR.w)));
}

__global__ __launch_bounds__(THREADS) void ssm2d_kernel(
    const float* __restrict__ x,
    const float* __restrict__ A1p, const float* __restrict__ A2p,
    const float* __restrict__ A3p, const float* __restrict__ A4p,
    const float* __restrict__ B1p, const float* __restrict__ B2p,
    const float* __restrict__ C1p, const float* __restrict__ C2p,
    const float* __restrict__ omega,
    float* __restrict__ out)
{
    __shared__ _Float16 u_lds[NPB * 1024];      // 16 KB fp16 input, XOR-swizzled
    __shared__ _Float16 p_lds[2 * NPB * 1024];  // 32 KB partials: [flip][img][pix]
    const int t = threadIdx.x;
    // XCD-aware remap (proven form)
    const int bid = blockIdx.x;
    const int m0  = ((bid & 7) * 256 + (bid >> 3)) * NPB;

    // ---- stage x into LDS (f32 -> fp16); XOR swizzle kills conflicts ----
    const int simg = t & 7;
    #pragma unroll 4
    for (int it = 0; it < 16; ++it) {
        int pix = it * 64 + (t >> 3);
        u_lds[simg * 1024 + (pix ^ (simg << 2))] =
            (_Float16)x[(size_t)pix * M_TOT + (m0 + simg)];
    }
    __syncthreads();

    const int j    = t & 31;
    const int slot = t >> 5;              // 0..15
    const int img  = slot >> 1;           // 0..7
    const int flip = slot & 1;            // 0 = pass A (rows asc), 1 = pass B
    const int m    = m0 + img;
    const int hb   = m & 63;
    const int colx = j ^ (img << 2);      // per-lane swizzled column
    const int colr = 31 ^ colx;           // reversed column's swizzled index
    const int fmask = flip ? 31 : 0;      // 31-s == s^31 for 5-bit s
    const _Float16* uim = u_lds + img * 1024;
    _Float16*       pim = p_lds + flip * (NPB * 1024) + img * 1024;
    const float om = omega[m & 1023];

    // dirs: flip=0 -> d0 (h=hb) + d2 (h=128+hb); flip=1 -> d1 (64+hb) + d3 (192+hb)
    DirPH PF, PR;
    dir_init_h(PF, hb + (flip << 6),       j, A1p, A2p, A3p, A4p, B1p, B2p, C1p, C2p);
    dir_init_h(PR, 128 + hb + (flip << 6), j, A1p, A2p, A3p, A4p, B1p, B2p, C1p, C2p);
    // per-lane epilogue constant: pass A folds om - k00F, pass B folds -k00F
    const float cF = (flip ? 0.f : om) - PF.k00;

    v2h xhF = {0,0}, xvF = {0,0}, cxF = {0,0};
    v2h xhR = {0,0}, xvR = {0,0}, cxR = {0,0};
    v2h up2 = {0,0}, upr2 = {0,0};
    #pragma unroll 4
    for (int s = 0; s < 32; ++s) {
        const int rr = s ^ fmask;         // logical row this slot processes
        _Float16 uh  = uim[rr * 32 + colx];
        _Float16 urh = uim[rr * 32 + colr];
        float uf = (float)uh, urf = (float)urh;
        v2h u2  = (v2h){uh, uh};
        v2h ur2 = (v2h){urh, urh};
        v2h nxvF, ncxF, dF, eF, nxvR, ncxR, dR, eR;
        dir_pre_h(PF, u2,  up2,  xhF, xvF, cxF, nxvF, ncxF, dF, eF);
        dir_pre_h(PR, ur2, upr2, xhR, xvR, cxR, nxvR, ncxR, dR, eR);
        unsigned f0 = h2u(dF), f1 = h2u(eF), r0 = h2u(dR), r1 = h2u(eR);
        scan4h(f0, f1, r0, r1, PF, PR);
        float yF = dir_post_h(PF, u2h(f0), u2h(f1), nxvF, ncxF,
                              xhF, xvF, cxF, 0.f);
        float yR = dir_post_h(PR, u2h(r0), u2h(r1), nxvR, ncxR,
                              xhR, xvR, cxR, -PR.k00 * urf);
        float yRf = swzrev(yR);           // lane reversal (off cross-row chain)
        pim[rr * 32 + colx] = (_Float16)fmaf(uf, cF, yF + yRf);
        up2 = u2; upr2 = ur2;
    }
    __syncthreads();

    // ---- fused combine + SiLU + coalesced store-out (f32) ----
    #pragma unroll 4
    for (int it = 0; it < 16; ++it) {
        int pix = it * 64 + (t >> 3);
        int idx = simg * 1024 + (pix ^ (simg << 2));
        float z  = (float)p_lds[idx] + (float)p_lds[NPB * 1024 + idx];
        float sg = 1.0f / (1.0f + __expf(-z));
        out[(size_t)pix * M_TOT + (m0 + simg)] = z * sg;
    }
}

extern "C" void kernel_launch(void* const* d_in, const int* in_sizes, int n_in,
                              void* d_out, int out_size, void* d_ws, size_t ws_size,
                              hipStream_t stream) {
    const float* x  = (const float*)d_in[0];
    const float* A1 = (const float*)d_in[1];
    const float* A2 = (const float*)d_in[2];
    const float* A3 = (const float*)d_in[3];
    const float* A4 = (const float*)d_in[4];
    const float* B1 = (const float*)d_in[5];
    const float* B2 = (const float*)d_in[6];
    const float* C1 = (const float*)d_in[7];
    const float* C2 = (const float*)d_in[8];
    const float* om = (const float*)d_in[9];
    float* out = (float*)d_out;
    hipLaunchKernelGGL(ssm2d_kernel, dim3(M_TOT / NPB), dim3(THREADS), 0, stream,
                       x, A1, A2, A3, A4, B1, B2, C1, C2, om, out);
}